// Round 2
// baseline (146.803 us; speedup 1.0000x reference)
//
#include <hip/hip_runtime.h>

#define SPB 2  // samples per block

__global__ __launch_bounds__(256, 8) void model_fused(
    const float* __restrict__ x, const float* __restrict__ y, const float* __restrict__ t,
    const float* __restrict__ embW1, const float* __restrict__ embb1,
    const float* __restrict__ embwa, const float* __restrict__ embwb,
    const float* __restrict__ embW2, const float* __restrict__ embb2,
    const float* __restrict__ mixW1, const float* __restrict__ mixb1,
    const float* __restrict__ mixwa, const float* __restrict__ mixwb,
    const float* __restrict__ mixW2, const float* __restrict__ mixb2,
    const float* __restrict__ outW0, const float* __restrict__ outb0,
    const float* __restrict__ outwa0, const float* __restrict__ outwb0,
    const float* __restrict__ outWh, const float* __restrict__ outbh,
    const float* __restrict__ outwah, const float* __restrict__ outwbh,
    const float* __restrict__ outWf1, const float* __restrict__ outbf1,
    const float* __restrict__ outwaf, const float* __restrict__ outwbf,
    const float* __restrict__ outWf2, const float* __restrict__ outbf2,
    float* __restrict__ out, int N)
{
    __shared__ float sC[3][64];        // per-channel region factors (region 0 == 1.0 implicit)
    __shared__ float sw[SPB][64];      // wave(u) per sample
    __shared__ float se[SPB][256];     // mixer output e
    __shared__ float pf[2][SPB][64];   // split-k partials for head layer 0
    __shared__ float sh[2][SPB][64];   // head double-buffer
    __shared__ float sMixW1[32], sMixb1[8], sMixW2[8];

    const int tid = threadIdx.x;
    const int n0  = blockIdx.x * SPB;

    // ---- stage tiny mixer params into LDS ----
    if (tid < 32)       sMixW1[tid]      = mixW1[tid];
    else if (tid < 40)  sMixb1[tid - 32] = mixb1[tid - 32];
    else if (tid < 48)  sMixW2[tid - 40] = mixW2[tid - 40];

    // ---- phase 1: region factors C_r[ch] and w = wave(u) per sample ----
    {
        const int ch = tid & 63;
        const int sm = tid >> 6;
        const float w0 = embW1[ch], w1 = embW1[64 + ch], w2 = embW1[128 + ch];
        if (sm < SPB) {
            const int n  = n0 + sm;
            const int ns = (n < N) ? n : (N - 1);
            float u = x[ns]*w0 + y[ns]*w1 + t[ns]*w2 + embb1[ch];
            sw[sm][ch] = embwa[0]*__sinf(u) + embwb[0]*__cosf(u);
        } else if (sm == 2) {
            // PERTS: symmetric grids -> <sin d> = 0, <cos d> factorizes per axis
            float ga = (1.f + 2.f*__cosf(0.01f*w0))
                     * (1.f + 2.f*__cosf(0.01f*w1))
                     * (1.f + 2.f*__cosf(0.01f*w2)) * (1.f/27.f);
            float gb = (1.f + 2.f*(__cosf(0.025f*w0) + __cosf(0.05f*w0)))
                     * (1.f + 2.f*(__cosf(0.025f*w1) + __cosf(0.05f*w1)))
                     * (1.f + 2.f*(__cosf(0.025f*w2) + __cosf(0.05f*w2))) * (1.f/125.f);
            sC[0][ch] = ga; sC[1][ch] = gb;
        } else {
            float gc = (1.f + 2.f*(__cosf(0.03f*w0) + __cosf(0.06f*w0) + __cosf(0.09f*w0)))
                     * (1.f + 2.f*(__cosf(0.03f*w1) + __cosf(0.06f*w1) + __cosf(0.09f*w1)))
                     * (1.f + 2.f*(__cosf(0.03f*w2) + __cosf(0.06f*w2) + __cosf(0.09f*w2))) * (1.f/343.f);
            sC[2][ch] = gc;
        }
    }
    __syncthreads();

    // ---- phase 2: 4-region projection (thread owns channel c) + inline mixer ----
    {
        const int c = tid;
        float a00=0.f,a01=0.f,a02=0.f,a03=0.f;
        float a10=0.f,a11=0.f,a12=0.f,a13=0.f;

        #pragma unroll 8
        for (int ch = 0; ch < 64; ++ch) {
            const float wr = embW2[ch*256 + c];          // coalesced across threads
            const float c1 = sC[0][ch], c2 = sC[1][ch], c3 = sC[2][ch];
            const float t0 = sw[0][ch] * wr;
            const float t1 = sw[1][ch] * wr;
            a00 += t0; a01 = fmaf(t0, c1, a01); a02 = fmaf(t0, c2, a02); a03 = fmaf(t0, c3, a03);
            a10 += t1; a11 = fmaf(t1, c1, a11); a12 = fmaf(t1, c2, a12); a13 = fmaf(t1, c3, a13);
        }

        const float mwa = mixwa[0], mwb = mixwb[0], mb2 = mixb2[0];
        const float bb2 = embb2[c];
        {
            const float s0 = a00+bb2, s1 = a01+bb2, s2 = a02+bb2, s3 = a03+bb2;
            float ev = mb2;
            #pragma unroll
            for (int j = 0; j < 8; ++j) {
                float p = fmaf(s0, sMixW1[j],
                          fmaf(s1, sMixW1[8 + j],
                          fmaf(s2, sMixW1[16 + j],
                          fmaf(s3, sMixW1[24 + j], sMixb1[j]))));
                ev = fmaf(mwa*__sinf(p) + mwb*__cosf(p), sMixW2[j], ev);
            }
            se[0][c] = ev;
        }
        {
            const float s0 = a10+bb2, s1 = a11+bb2, s2 = a12+bb2, s3 = a13+bb2;
            float ev = mb2;
            #pragma unroll
            for (int j = 0; j < 8; ++j) {
                float p = fmaf(s0, sMixW1[j],
                          fmaf(s1, sMixW1[8 + j],
                          fmaf(s2, sMixW1[16 + j],
                          fmaf(s3, sMixW1[24 + j], sMixb1[j]))));
                ev = fmaf(mwa*__sinf(p) + mwb*__cosf(p), sMixW2[j], ev);
            }
            se[1][c] = ev;
        }
    }
    __syncthreads();

    // ---- phase 3: output head ----
    // layer 0 (256 -> 64): split-k across halves so all 4 waves work
    {
        const int h = tid >> 7;          // which k-half
        const int r = tid & 127;
        const int n = r >> 6, f = r & 63;
        const int k0 = h * 128;
        float p = 0.f;
        #pragma unroll 8
        for (int k = 0; k < 128; ++k)
            p = fmaf(se[n][k0 + k], outW0[(k0 + k)*64 + f], p);  // se broadcast (wave-uniform n)
        pf[h][n][f] = p;
    }
    __syncthreads();

    const int n = (tid >> 6) & 1, f = tid & 63;
    if (tid < 128) {
        float a = pf[0][n][f] + pf[1][n][f] + outb0[f];
        sh[0][n][f] = outwa0[0]*__sinf(a) + outwb0[0]*__cosf(a);
    }
    __syncthreads();

    int cur = 0;
    #pragma unroll
    for (int i = 0; i < 3; ++i) {
        if (tid < 128) {
            float a = outbh[i*64 + f];
            const float* W = outWh + i*4096;
            #pragma unroll 8
            for (int k = 0; k < 64; ++k)
                a = fmaf(sh[cur][n][k], W[k*64 + f], a);
            sh[1 - cur][n][f] = outwah[i]*__sinf(a) + outwbh[i]*__cosf(a);
        }
        __syncthreads();
        cur ^= 1;
    }
    if (tid < 128) {
        float a = outbf1[f];
        #pragma unroll 8
        for (int k = 0; k < 64; ++k)
            a = fmaf(sh[cur][n][k], outWf1[k*64 + f], a);
        sh[1 - cur][n][f] = outwaf[0]*__sinf(a) + outwbf[0]*__cosf(a);
    }
    __syncthreads();
    cur ^= 1;

    if (tid < SPB*3) {
        const int nn = tid / 3, o = tid - nn*3;
        float a = outbf2[o];
        #pragma unroll 8
        for (int k = 0; k < 64; ++k)
            a = fmaf(sh[cur][nn][k], outWf2[k*3 + o], a);
        const int gn = n0 + nn;
        if (gn < N) out[gn*3 + o] = a;
    }
}

extern "C" void kernel_launch(void* const* d_in, const int* in_sizes, int n_in,
                              void* d_out, int out_size, void* d_ws, size_t ws_size,
                              hipStream_t stream) {
    const float* x      = (const float*)d_in[0];
    const float* y      = (const float*)d_in[1];
    const float* t      = (const float*)d_in[2];
    const float* embW1  = (const float*)d_in[3];
    const float* embb1  = (const float*)d_in[4];
    const float* embwa  = (const float*)d_in[5];
    const float* embwb  = (const float*)d_in[6];
    const float* embW2  = (const float*)d_in[7];
    const float* embb2  = (const float*)d_in[8];
    const float* mixW1  = (const float*)d_in[9];
    const float* mixb1  = (const float*)d_in[10];
    const float* mixwa  = (const float*)d_in[11];
    const float* mixwb  = (const float*)d_in[12];
    const float* mixW2  = (const float*)d_in[13];
    const float* mixb2  = (const float*)d_in[14];
    const float* outW0  = (const float*)d_in[15];
    const float* outb0  = (const float*)d_in[16];
    const float* outwa0 = (const float*)d_in[17];
    const float* outwb0 = (const float*)d_in[18];
    const float* outWh  = (const float*)d_in[19];
    const float* outbh  = (const float*)d_in[20];
    const float* outwah = (const float*)d_in[21];
    const float* outwbh = (const float*)d_in[22];
    const float* outWf1 = (const float*)d_in[23];
    const float* outbf1 = (const float*)d_in[24];
    const float* outwaf = (const float*)d_in[25];
    const float* outwbf = (const float*)d_in[26];
    const float* outWf2 = (const float*)d_in[27];
    const float* outbf2 = (const float*)d_in[28];
    float* out = (float*)d_out;

    const int N = in_sizes[0];
    const int blocks = (N + SPB - 1) / SPB;
    model_fused<<<blocks, 256, 0, stream>>>(
        x, y, t,
        embW1, embb1, embwa, embwb, embW2, embb2,
        mixW1, mixb1, mixwa, mixwb, mixW2, mixb2,
        outW0, outb0, outwa0, outwb0,
        outWh, outbh, outwah, outwbh,
        outWf1, outbf1, outwaf, outwbf, outWf2, outbf2,
        out, N);
}